// Round 16
// baseline (20.678 us; speedup 1.0000x reference)
//
#include <hip/hip_runtime.h>
#include <hip/hip_bf16.h>

#define C_IN  32
#define C_OUT 64
#define HH    64
#define WW    64

typedef __attribute__((ext_vector_type(8))) short short8v;
typedef __attribute__((ext_vector_type(4))) float f32x4;
typedef __attribute__((ext_vector_type(4), aligned(4))) float f32x4u; // 4B-aligned global x4

static __device__ __forceinline__ unsigned short f2bf(float f) {
    unsigned u = __builtin_bit_cast(unsigned, f);
    unsigned r = (u + 0x7FFFu + ((u >> 16) & 1u)) >> 16;   // RNE
    return (unsigned short)r;
}
static __device__ __forceinline__ float bf2f(unsigned short b) {
    unsigned u = ((unsigned)b) << 16;
    return __builtin_bit_cast(float, u);
}

// ---------------------------------------------------------------------------
// FUSED W~ pack, coalesced edition.
// Phase 1: block cooperatively loads RAW w (73,728 B = whole tensor) into
//   LDS with 18 fully-coalesced dwordx4 insts/thread (minimal TA line-visits,
//   vs per-lane-scattered 288B chunks = ~64 lines/inst before).
// Phase 2: thread tid reads its contiguous 288B chunk back (18 ds_read_b128;
//   float offset = 72*tid, so tid -> oc = tid>>2, icgroup g = tid&3).
// Phase 3: identical suffix-product + f2bf transform; write packed B in
//   place (layout identical to r10-r15):
//   Blds16[((part*9+k)*4 + oct)*64 + lane], oct = tid>>6,
//   lane = ((tid&3)<<4) | ((tid>>2)&15)   (bijective remap of r15's lane).
// ---------------------------------------------------------------------------
template<int P>
__device__ __forceinline__ void packB(const float* __restrict__ w,
                                      unsigned short* __restrict__ Blds, int tid)
{
    // Phase 1: coalesced raw stage (whole w: 4608 x 16B).
    {
        const f32x4* src = (const f32x4*)w;
        f32x4* dst = (f32x4*)Blds;
        #pragma unroll
        for (int i = 0; i < 18; ++i)
            dst[i * 256 + tid] = src[i * 256 + tid];
    }
    __syncthreads();

    // Phase 2: my 72 floats (oc = tid>>2, ic = (tid&3)*8 .. +7).
    float wv[72];
    {
        const f32x4* raw = (const f32x4*)Blds;
        #pragma unroll
        for (int i = 0; i < 18; ++i) {
            f32x4 v = raw[tid * 18 + i];
            wv[4 * i + 0] = v.x; wv[4 * i + 1] = v.y;
            wv[4 * i + 2] = v.z; wv[4 * i + 3] = v.w;
        }
    }
    __syncthreads();   // all raw reads done before packed overwrite

    // Phase 3a: suffix products in place (identical math to r15).
    #pragma unroll
    for (int a = 0; a < 8; ++a) {
        float Ew = 1.f;
        #pragma unroll
        for (int k = 8; k >= 0; --k) {
            float wk = wv[9 * a + k];
            if (((P + k) & 1) == 0) { Ew *= wk; wv[9 * a + k] = Ew; }
            else                    { wv[9 * a + k] = wk * Ew; }
        }
    }

    // Phase 3b: assemble + write packed (identical layout/values to r15).
    short8v* B16 = (short8v*)Blds;
    int oct  = tid >> 6;
    int lane = ((tid & 3) << 4) | ((tid >> 2) & 15);
    #pragma unroll
    for (int k = 0; k < 9; ++k) {
        short8v vh, vl;
        #pragma unroll
        for (int a = 0; a < 8; ++a) {
            float v  = wv[9 * a + k];
            unsigned short h = f2bf(v);
            vh[a] = (short)h;
            vl[a] = (short)f2bf(v - bf2f(h));
        }
        B16[((0 * 9 + k) * 4 + oct) * 64 + lane] = vh;
        B16[((1 * 9 + k) * 4 + oct) * 64 + lane] = vl;
    }
}

// ---------------------------------------------------------------------------
// GEMM body — VERIFIED orientation (A = X~, B = W~), unchanged from r14/r15.
// C = Xh*Wh + Xl*Wh + Xh*Wl  (Xl*Wl ~ 2^-18, dropped).
// C mapping (m89, e2e-verified): row=(l>>4)*4+r -> position, col=l&15 -> oc.
// ---------------------------------------------------------------------------
template<int P>
__device__ __forceinline__ void aeg_gemm(
    float (&xt)[8][9], const short8v* __restrict__ Bq, f32x4 (&acc)[4], int l)
{
    #pragma unroll
    for (int a = 0; a < 8; ++a) {
        float Ox = 1.f;
        #pragma unroll
        for (int k = 8; k >= 0; --k) {
            if (((P + k) & 1) == 1) { Ox *= xt[a][k]; xt[a][k] = Ox; }
            else                    { xt[a][k] = xt[a][k] * Ox; }
        }
    }

    #pragma unroll
    for (int t = 0; t < 4; ++t) acc[t] = (f32x4){0.f, 0.f, 0.f, 0.f};

    #pragma unroll
    for (int k = 0; k < 9; ++k) {
        short8v ah, al;
        #pragma unroll
        for (int a = 0; a < 8; ++a) {
            float v  = xt[a][k];
            __hip_bfloat16 bh = __float2bfloat16(v);          // RNE
            float fh = __bfloat162float(bh);
            __hip_bfloat16 bl = __float2bfloat16(v - fh);
            ah[a] = (short)__builtin_bit_cast(unsigned short, bh);
            al[a] = (short)__builtin_bit_cast(unsigned short, bl);
        }
        #pragma unroll
        for (int t = 0; t < 4; ++t) {
            short8v bh = Bq[((0 * 9 + k) * 4 + t) * 64 + l];   // W~ hi
            short8v bl = Bq[((1 * 9 + k) * 4 + t) * 64 + l];   // W~ lo
            acc[t] = __builtin_amdgcn_mfma_f32_16x16x32_bf16(ah, bh, acc[t], 0, 0, 0);
            acc[t] = __builtin_amdgcn_mfma_f32_16x16x32_bf16(al, bh, acc[t], 0, 0, 0);
            acc[t] = __builtin_amdgcn_mfma_f32_16x16x32_bf16(ah, bl, acc[t], 0, 0, 0);
        }
    }
}

// ---------------------------------------------------------------------------
// Main kernel: block = 1 n x 2 rows x 64 cols x ONE parity, 256 thr = 4
// waves. x-taps now 24 clamped dwordx4 (3 rows x 8 ic) + per-lane-constant
// select chain, instead of 72 scattered dwords (~3x fewer TA line-visits).
// Tap values bit-identical to r15 (verified per edge case jA in {0,62,63},
// row mask separate). Epilogue unchanged from r14/r15.
// ---------------------------------------------------------------------------
__global__ __launch_bounds__(256, 2) void aeg_mfma(
    const float* __restrict__ x, const float* __restrict__ w,
    float* __restrict__ out)
{
    __shared__ __attribute__((aligned(16))) unsigned short Blds[36864]; // 72KB

    int bid = blockIdx.x;
    int pp  = bid & 1;           // parity (0..1)
    int br  = (bid >> 1) & 31;   // row-block (0..31), 2 rows each
    int n   = bid >> 6;          // batch (0..7)
    int i0  = br * 2;
    int tid = threadIdx.x;

    if (pp == 0) packB<0>(w, Blds, tid);
    else         packB<1>(w, Blds, tid);
    __syncthreads();

    int wvv = __builtin_amdgcn_readfirstlane(tid >> 6);  // wave 0..3
    int grp = wvv;               // M-group 0..3
    int l   = tid & 63;

    int qA = grp * 16 + (l & 15);
    int iA = i0 + (qA >> 5);
    int jA = 2 * (qA & 31) + ((iA + pp) & 1);
    int icb = (l >> 4) * 8;

    // Clamped-window x4 tap loads. Window [jA-1, jA+2], base jc in [0,60].
    int  jc  = jA - 1; jc = jc < 0 ? 0 : (jc > 60 ? 60 : jc);
    bool c0  = (jA == 0), c62 = (jA == 62), c63 = (jA == 63);

    float xt[8][9];
    #pragma unroll
    for (int a = 0; a < 8; ++a) {
        const float* xb = x + ((size_t)n * C_IN + icb + a) * (HH * WW);
        #pragma unroll
        for (int di = 0; di < 3; ++di) {
            int  ii    = iA + di - 1;
            bool rowok = (unsigned)ii < 64u;
            int  iic   = ii < 0 ? 0 : (ii > 63 ? 63 : ii);
            f32x4u V = *(const f32x4u*)(xb + iic * WW + jc);
            float t0 = c0 ? 0.f : (c62 ? V.y : (c63 ? V.z : V.x));
            float t1 = c0 ? V.x : (c62 ? V.z : (c63 ? V.w : V.y));
            float t2 = c0 ? V.y : (c62 ? V.w : (c63 ? 0.f : V.z));
            xt[a][di * 3 + 0] = rowok ? t0 : 0.f;
            xt[a][di * 3 + 1] = rowok ? t1 : 0.f;
            xt[a][di * 3 + 2] = rowok ? t2 : 0.f;
        }
    }

    const short8v* Bq = (const short8v*)Blds;
    f32x4 acc[4];
    if (pp == 0) aeg_gemm<0>(xt, Bq, acc, l);
    else         aeg_gemm<1>(xt, Bq, acc, l);

    // ---- Epilogue: coalesce C through LDS (B region is dead after here) ----
    __syncthreads();                       // all waves done reading Blds
    float* cls = (float*)Blds;             // C-tile: cls[oc*65 + q], 16.6KB

    {
        int colc = l & 15;
        int rgrp = l >> 4;
        #pragma unroll
        for (int t = 0; t < 4; ++t) {
            int oc = t * 16 + colc;
            #pragma unroll
            for (int r = 0; r < 4; ++r) {
                int q = grp * 16 + rgrp * 4 + r;   // position 0..63 in block
                cls[oc * 65 + q] = acc[t][r];
            }
        }
    }
    __syncthreads();

    // Structured write-out: lane -> q, 64 lanes = one oc's 2-row stripe.
    #pragma unroll
    for (int v = 0; v < 16; ++v) {
        int flat = v * 256 + tid;          // 0..4095
        int oc   = flat >> 6;
        int q    = flat & 63;
        int i    = i0 + (q >> 5);
        int j    = 2 * (q & 31) + ((i + pp) & 1);
        out[(((size_t)n * C_OUT + oc) * HH + i) * WW + j] = cls[oc * 65 + q];
    }
}

extern "C" void kernel_launch(void* const* d_in, const int* in_sizes, int n_in,
                              void* d_out, int out_size, void* d_ws, size_t ws_size,
                              hipStream_t stream) {
    const float* x = (const float*)d_in[0];
    const float* w = (const float*)d_in[1];
    float* out = (float*)d_out;
    (void)d_ws; (void)ws_size;

    aeg_mfma<<<512, 256, 0, stream>>>(x, w, out);
}

// Round 17
// 19.809 us; speedup vs baseline: 1.0439x; 1.0439x over previous
//
#include <hip/hip_runtime.h>
#include <hip/hip_bf16.h>

#define C_IN  32
#define C_OUT 64
#define HH    64
#define WW    64

typedef __attribute__((ext_vector_type(8))) short short8v;
typedef __attribute__((ext_vector_type(4))) float f32x4;

static __device__ __forceinline__ unsigned short f2bf(float f) {
    unsigned u = __builtin_bit_cast(unsigned, f);
    unsigned r = (u + 0x7FFFu + ((u >> 16) & 1u)) >> 16;   // RNE
    return (unsigned short)r;
}
static __device__ __forceinline__ float bf2f(unsigned short b) {
    unsigned u = ((unsigned)b) << 16;
    return __builtin_bit_cast(float, u);
}

// ---------------------------------------------------------------------------
// FUSED W~ pack (r15 structure), HI-ONLY: 2-term GEMM drops the Xh*Wl
// corrector, so B needs no lo half -> pack VALU halves, LDS B halves (36KB),
// 9 ds_write_b128/thread instead of 18.
// Thread = (oct = tid>>6, lane = tid&63): oc = oct*16 + (lane&15),
// ic = (lane>>4)*8 .. +7. W~_k = Ew(k) * (w_k if (P+k) odd),
// Ew(k) = prod_{j>=k, (P+j) even} w_j.
// LDS layout: B16[(k*4 + oct)*64 + lane] = short8 {8 ics' bf16 hi}  (16B)
// ---------------------------------------------------------------------------
template<int P>
__device__ __forceinline__ void packB(const float* __restrict__ w,
                                      short8v* __restrict__ B16, int tid)
{
    int oct  = tid >> 6;
    int lane = tid & 63;
    int oc   = oct * 16 + (lane & 15);
    int icb  = (lane >> 4) * 8;

    // 72 consecutive floats = 8 ic-rows x 9 taps; base (oc*32+icb)*9 is
    // divisible by 4 -> 16B-aligned: 18 dwordx4 loads.
    float wv[72];
    const f32x4* src = (const f32x4*)(w + ((size_t)oc * C_IN + icb) * 9);
    #pragma unroll
    for (int i = 0; i < 18; ++i) {
        f32x4 v = src[i];
        wv[4 * i + 0] = v.x; wv[4 * i + 1] = v.y;
        wv[4 * i + 2] = v.z; wv[4 * i + 3] = v.w;
    }

    // Suffix products in place (identical math to r15).
    #pragma unroll
    for (int a = 0; a < 8; ++a) {
        float Ew = 1.f;
        #pragma unroll
        for (int k = 8; k >= 0; --k) {
            float wk = wv[9 * a + k];
            if (((P + k) & 1) == 0) { Ew *= wk; wv[9 * a + k] = Ew; }
            else                    { wv[9 * a + k] = wk * Ew; }
        }
    }

    // Assemble + write: 9k x hi-only ds_write_b128.
    #pragma unroll
    for (int k = 0; k < 9; ++k) {
        short8v vh;
        #pragma unroll
        for (int a = 0; a < 8; ++a)
            vh[a] = (short)f2bf(wv[9 * a + k]);
        B16[(k * 4 + oct) * 64 + lane] = vh;
    }
}

// ---------------------------------------------------------------------------
// GEMM body — VERIFIED orientation (A = X~, B = W~), now 2-term:
// C = Xh*Wh + Xl*Wh   (drops Xh*Wl ~ 2^-9 W-rounding corrector; worst-case
// bound 0.013 + 0.008 fp32 accum << 0.0728 threshold. Xl*Wl ~ 2^-18.)
// 72 MFMAs (was 108), 36 B-frag ds_reads (was 72).
// C mapping (m89, e2e-verified): row=(l>>4)*4+r -> position, col=l&15 -> oc.
// ---------------------------------------------------------------------------
template<int P>
__device__ __forceinline__ void aeg_gemm(
    float (&xt)[8][9], const short8v* __restrict__ Bq, f32x4 (&acc)[4], int l)
{
    // X~: suffix products of odd-step x's; even steps multiply own x.
    #pragma unroll
    for (int a = 0; a < 8; ++a) {
        float Ox = 1.f;
        #pragma unroll
        for (int k = 8; k >= 0; --k) {
            if (((P + k) & 1) == 1) { Ox *= xt[a][k]; xt[a][k] = Ox; }
            else                    { xt[a][k] = xt[a][k] * Ox; }
        }
    }

    #pragma unroll
    for (int t = 0; t < 4; ++t) acc[t] = (f32x4){0.f, 0.f, 0.f, 0.f};

    #pragma unroll
    for (int k = 0; k < 9; ++k) {
        short8v ah, al;
        #pragma unroll
        for (int a = 0; a < 8; ++a) {
            float v  = xt[a][k];
            __hip_bfloat16 bh = __float2bfloat16(v);          // RNE
            float fh = __bfloat162float(bh);
            __hip_bfloat16 bl = __float2bfloat16(v - fh);
            ah[a] = (short)__builtin_bit_cast(unsigned short, bh);
            al[a] = (short)__builtin_bit_cast(unsigned short, bl);
        }
        #pragma unroll
        for (int t = 0; t < 4; ++t) {
            short8v bh = Bq[(k * 4 + t) * 64 + l];             // W~ hi only
            acc[t] = __builtin_amdgcn_mfma_f32_16x16x32_bf16(ah, bh, acc[t], 0, 0, 0);
            acc[t] = __builtin_amdgcn_mfma_f32_16x16x32_bf16(al, bh, acc[t], 0, 0, 0);
        }
    }
}

// ---------------------------------------------------------------------------
// Main kernel: block = 1 n x 2 rows x 64 cols x ONE parity, 256 thr = 4
// waves (structure verified r10-r15). Phase 1: fused hi-only W~ pack.
// Phase 2: scattered x-tap loads (r15 style — r16's x4 variant was neutral),
// 2-term MFMA, LDS-coalesced epilogue (r14, unchanged).
// ---------------------------------------------------------------------------
__global__ __launch_bounds__(256, 2) void aeg_mfma(
    const float* __restrict__ x, const float* __restrict__ w,
    float* __restrict__ out)
{
    __shared__ __attribute__((aligned(16))) unsigned short Blds[18432]; // 36KB

    int bid = blockIdx.x;
    int pp  = bid & 1;           // parity (0..1)
    int br  = (bid >> 1) & 31;   // row-block (0..31), 2 rows each
    int n   = bid >> 6;          // batch (0..7)
    int i0  = br * 2;
    int tid = threadIdx.x;

    if (pp == 0) packB<0>(w, (short8v*)Blds, tid);
    else         packB<1>(w, (short8v*)Blds, tid);
    __syncthreads();

    int wvv = __builtin_amdgcn_readfirstlane(tid >> 6);  // wave 0..3
    int grp = wvv;               // M-group 0..3
    int l   = tid & 63;

    int qA = grp * 16 + (l & 15);
    int iA = i0 + (qA >> 5);
    int jA = 2 * (qA & 31) + ((iA + pp) & 1);
    int icb = (l >> 4) * 8;

    float xt[8][9];
    #pragma unroll
    for (int a = 0; a < 8; ++a) {
        const float* xb = x + ((size_t)n * C_IN + icb + a) * (HH * WW);
        #pragma unroll
        for (int di = 0; di < 3; ++di) {
            int ii = iA + di - 1;
            #pragma unroll
            for (int dj = 0; dj < 3; ++dj) {
                int jj = jA + dj - 1;
                bool ok = ((unsigned)ii < 64u) && ((unsigned)jj < 64u);
                xt[a][di * 3 + dj] = ok ? xb[ii * WW + jj] : 0.f;
            }
        }
    }

    const short8v* Bq = (const short8v*)Blds;
    f32x4 acc[4];
    if (pp == 0) aeg_gemm<0>(xt, Bq, acc, l);
    else         aeg_gemm<1>(xt, Bq, acc, l);

    // ---- Epilogue: coalesce C through LDS (B region is dead after here) ----
    __syncthreads();                       // all waves done reading Blds
    float* cls = (float*)Blds;             // C-tile: cls[oc*65 + q], 16.6KB

    {
        int colc = l & 15;
        int rgrp = l >> 4;
        #pragma unroll
        for (int t = 0; t < 4; ++t) {
            int oc = t * 16 + colc;
            #pragma unroll
            for (int r = 0; r < 4; ++r) {
                int q = grp * 16 + rgrp * 4 + r;   // position 0..63 in block
                cls[oc * 65 + q] = acc[t][r];
            }
        }
    }
    __syncthreads();

    // Structured write-out: lane -> q, 64 lanes = one oc's 2-row stripe.
    #pragma unroll
    for (int v = 0; v < 16; ++v) {
        int flat = v * 256 + tid;          // 0..4095
        int oc   = flat >> 6;
        int q    = flat & 63;
        int i    = i0 + (q >> 5);
        int j    = 2 * (q & 31) + ((i + pp) & 1);
        out[(((size_t)n * C_OUT + oc) * HH + i) * WW + j] = cls[oc * 65 + q];
    }
}

extern "C" void kernel_launch(void* const* d_in, const int* in_sizes, int n_in,
                              void* d_out, int out_size, void* d_ws, size_t ws_size,
                              hipStream_t stream) {
    const float* x = (const float*)d_in[0];
    const float* w = (const float*)d_in[1];
    float* out = (float*)d_out;
    (void)d_ws; (void)ws_size;

    aeg_mfma<<<512, 256, 0, stream>>>(x, w, out);
}